// Round 7
// baseline (162.982 us; speedup 1.0000x reference)
//
#include <hip/hip_runtime.h>
#include <hip/hip_bf16.h>

typedef __bf16 bf16x8 __attribute__((ext_vector_type(8)));
typedef unsigned short u16x8 __attribute__((ext_vector_type(8)));
typedef unsigned short u16x4 __attribute__((ext_vector_type(4)));
typedef float f32x4 __attribute__((ext_vector_type(4)));

#define MFMA(a, b, c) __builtin_amdgcn_mfma_f32_16x16x32_bf16(a, b, c, 0, 0, 0)

#define LQ 2048
#define DD 256

static __device__ __forceinline__ float bf2f(unsigned short u) {
  union { unsigned int i; float f; } x; x.i = ((unsigned int)u) << 16; return x.f;
}
static __device__ __forceinline__ unsigned short f2bf(float f) {
  union { float f; unsigned int i; } x; x.f = f;
  unsigned int r = x.i + 0x7fffu + ((x.i >> 16) & 1u);  // RNE
  return (unsigned short)(r >> 16);
}
static __device__ __forceinline__ void gll16(const void* g, void* l) {
  __builtin_amdgcn_global_load_lds(
      (const __attribute__((address_space(1))) unsigned int*)g,
      (__attribute__((address_space(3))) unsigned int*)l, 16, 0, 0);
}

// ---------- weight transpose: W f32 [K][N] -> WT bf16 [N][K] ----------
__global__ void wt_kernel(const float* __restrict__ W, unsigned short* __restrict__ WT,
                          int logK, int N) {
  int K = 1 << logK;
  int id = blockIdx.x * 256 + threadIdx.x;
  if (id >= K * N) return;
  int n = id >> logK;
  int k = id & (K - 1);
  WT[id] = f2bf(W[(long)k * N + n]);
}

// ---------- projection GEMM: out bf16[M][256] = A f32[M][Kd] @ W (+bias) ----------
__global__ __launch_bounds__(256) void proj_kernel(
    const float* __restrict__ A, const unsigned short* __restrict__ WT,
    const float* __restrict__ bias, unsigned short* __restrict__ outb,
    unsigned short* __restrict__ outT, int Kd) {
  __shared__ unsigned short A_s[128 * 32];
  __shared__ unsigned short B_s[128 * 32];
  const int tid = threadIdx.x;
  const int w = tid >> 6, lane = tid & 63, g = lane >> 4, c = lane & 15;
  const int m0 = (blockIdx.x >> 1) * 128, n0 = (blockIdx.x & 1) * 128;
  const int wr = (w >> 1) * 64, wc = (w & 1) * 64;

  f32x4 acc[4][4];
  const f32x4 z4 = {0.f, 0.f, 0.f, 0.f};
  for (int i = 0; i < 4; i++)
    for (int j = 0; j < 4; j++) acc[i][j] = z4;

  const int row_st = tid >> 1, k0 = (tid & 1) * 16;
  const unsigned swz_w = (unsigned)((row_st & 7) << 4);
  const int nk = Kd >> 5;
  for (int ks = 0; ks < nk; ks++) {
    {
      const float* src = A + (long)(m0 + row_st) * Kd + ks * 32 + k0;
      f32x4 a0 = *(const f32x4*)(src);
      f32x4 a1 = *(const f32x4*)(src + 4);
      f32x4 a2 = *(const f32x4*)(src + 8);
      f32x4 a3 = *(const f32x4*)(src + 12);
      bf16x8 t0, t1;
#pragma unroll
      for (int j = 0; j < 4; j++) {
        t0[j] = (__bf16)a0[j]; t0[4 + j] = (__bf16)a1[j];
        t1[j] = (__bf16)a2[j]; t1[4 + j] = (__bf16)a3[j];
      }
      *(bf16x8*)((char*)A_s + (((unsigned)(row_st * 64 + k0 * 2)) ^ swz_w)) = t0;
      *(bf16x8*)((char*)A_s + (((unsigned)(row_st * 64 + k0 * 2 + 16)) ^ swz_w)) = t1;
      const unsigned short* srcB = WT + (long)(n0 + row_st) * Kd + ks * 32 + k0;
      u16x8 b0 = *(const u16x8*)srcB;
      u16x8 b1 = *(const u16x8*)(srcB + 8);
      *(u16x8*)((char*)B_s + (((unsigned)(row_st * 64 + k0 * 2)) ^ swz_w)) = b0;
      *(u16x8*)((char*)B_s + (((unsigned)(row_st * 64 + k0 * 2 + 16)) ^ swz_w)) = b1;
    }
    __syncthreads();
    bf16x8 af[4], bfr[4];
    for (int rf = 0; rf < 4; rf++) {
      int row = wr + rf * 16 + c;
      af[rf] = *(const bf16x8*)((char*)A_s +
                (((unsigned)(row * 64 + g * 16)) ^ ((row & 7) << 4)));
    }
    for (int cf = 0; cf < 4; cf++) {
      int row = wc + cf * 16 + c;
      bfr[cf] = *(const bf16x8*)((char*)B_s +
                (((unsigned)(row * 64 + g * 16)) ^ ((row & 7) << 4)));
    }
    for (int rf = 0; rf < 4; rf++)
      for (int cf = 0; cf < 4; cf++)
        acc[rf][cf] = MFMA(af[rf], bfr[cf], acc[rf][cf]);
    __syncthreads();
  }
  for (int cf = 0; cf < 4; cf++) {
    const int col = n0 + wc + cf * 16 + c;
    const float bv = bias[col];
    for (int rf = 0; rf < 4; rf++) {
      const int row0 = m0 + wr + rf * 16 + g * 4;
      unsigned short pk[4];
      for (int i = 0; i < 4; i++) {
        float v = acc[rf][cf][i] + bv;
        pk[i] = f2bf(v);
        outb[(long)(row0 + i) * 256 + col] = pk[i];
      }
      if (outT) {
        const int b = row0 >> 11;
        const int key0 = row0 & 2047;
        unsigned long long packed = (unsigned long long)pk[0] |
                                    ((unsigned long long)pk[1] << 16) |
                                    ((unsigned long long)pk[2] << 32) |
                                    ((unsigned long long)pk[3] << 48);
        *(unsigned long long*)(outT + ((long)(b * 256 + col) * LQ + key0)) = packed;
      }
    }
  }
}

// ---------- flash attention: 16 q-rows/wave, single-buffer LDS, NSPLIT ----
// Block: 4 waves x 16 rows = 64 q-rows; keys [ksplit*2048/NSPLIT, +..).
// LDS 36KB -> 3 blocks/CU (VGPR-capped 3 waves/SIMD = 12 waves/CU).
// Ks slot (ks,g,key): byte ks*2048+g*512+key*16 = K[k0+key][ks*32+g*8..+8]
// KTs slot (f,g,c):   byte f*1024+g*256+c*16   = KT[f*16+c][k0+g*8..+8]
template <int NSPLIT>
__global__ __launch_bounds__(256, 3) void attn_kernel(
    const unsigned short* __restrict__ Qb, const unsigned short* __restrict__ Kb,
    const unsigned short* __restrict__ KTb, unsigned short* __restrict__ Op,
    float* __restrict__ out, float* __restrict__ ML) {
  constexpr int KS = 2048 / NSPLIT;   // keys per block
  constexpr int NT = KS / 32;         // 32-key tiles
  constexpr int NBLK = 256 * NSPLIT;  // grid size
  __shared__ char Ks[16384];
  __shared__ char KTs[16384];
  __shared__ char Ps[4][1024];
  const int tid = threadIdx.x;
  const int w = tid >> 6, lane = tid & 63, g = lane >> 4, c = lane & 15;
  const int lid = (blockIdx.x & 7) * (NBLK / 8) + (blockIdx.x >> 3);  // XCD-chunked
  const int ksplit = lid & (NSPLIT - 1), qg = lid / NSPLIT;  // qg 0..255
  const int b = qg >> 5;
  const long qrow0 = (long)qg * 64;
  const int kbase = ksplit * KS;
  const float CS = 0.03125f * 1.4426950408889634f;  // SCALE * log2(e)
  const float THRM = 8.0f / CS;                     // defer-max threshold (raw)

  bf16x8 qa[8];
  {
    const unsigned short* qr = Qb + (qrow0 + w * 16 + c) * DD + g * 8;
#pragma unroll
    for (int ks = 0; ks < 8; ks++) qa[ks] = *(const bf16x8*)(qr + ks * 32);
  }
  f32x4 o[16];
  const f32x4 z4 = {0.f, 0.f, 0.f, 0.f};
#pragma unroll
  for (int f = 0; f < 16; f++) o[f] = z4;
  float m_[4] = {-1e30f, -1e30f, -1e30f, -1e30f};
  float l_[4] = {0.f, 0.f, 0.f, 0.f};

  const char* kb_b = (const char*)(Kb + (long)b * LQ * DD);
  const char* kt_b = (const char*)(KTb + (long)b * DD * LQ);

  const int ks_w = w >> 1;
  const int kg_w = ((w & 1) << 1) + (lane >> 5);
  const int kkey = lane & 31;

#define STAGE(kt_)                                                              \
  {                                                                             \
    const int k0_ = kbase + (kt_) * 32;                                         \
    _Pragma("unroll") for (int i = 0; i < 4; i++) {                             \
      gll16(kb_b + (long)(k0_ + kkey) * 512 + (i * 2 + ks_w) * 64 + kg_w * 16,  \
            Ks + i * 4096 + w * 1024);                                          \
    }                                                                           \
    _Pragma("unroll") for (int i = 0; i < 4; i++) {                             \
      const int f_ = i * 4 + w;                                                 \
      gll16(kt_b + (long)(f_ * 16 + c) * 4096 + (long)k0_ * 2 + g * 16,         \
            KTs + f_ * 1024);                                                   \
    }                                                                           \
  }

  for (int kt = 0; kt < NT; kt++) {
    __syncthreads();               // all waves done reading previous tile
    STAGE(kt);
    __syncthreads();               // vmcnt drain: tile staged

    // ---- S = Q K^T ----
    const char* kread = Ks + g * 512 + c * 16;
    f32x4 s0 = z4, s1 = z4;
#pragma unroll
    for (int ks = 0; ks < 8; ks++) {
      bf16x8 kb0 = *(const bf16x8*)(kread + ks * 2048);
      bf16x8 kb1 = *(const bf16x8*)(kread + ks * 2048 + 256);
      s0 = MFMA(qa[ks], kb0, s0);
      s1 = MFMA(qa[ks], kb1, s1);
    }
    // ---- online softmax with defer-max ----
    float m2[4];
#pragma unroll
    for (int i = 0; i < 4; i++) m2[i] = fmaxf(s0[i], s1[i]);
#pragma unroll
    for (int msk = 1; msk <= 8; msk <<= 1)
#pragma unroll
      for (int i = 0; i < 4; i++) m2[i] = fmaxf(m2[i], __shfl_xor(m2[i], msk, 64));
    bool grew = (m2[0] > m_[0] + THRM) | (m2[1] > m_[1] + THRM) |
                (m2[2] > m_[2] + THRM) | (m2[3] > m_[3] + THRM);
    if (__any(grew)) {
#pragma unroll
      for (int i = 0; i < 4; i++) {
        float mn = fmaxf(m_[i], m2[i]);
        float al = exp2f((m_[i] - mn) * CS);
        m_[i] = mn;
        l_[i] *= al;
#pragma unroll
        for (int f = 0; f < 16; f++) o[f][i] *= al;
      }
    }
    // ---- P -> LDS, read back as A-frag ----
#pragma unroll
    for (int i = 0; i < 4; i++) {
      const int row = 4 * g + i;
      const unsigned swz = (unsigned)(i << 4);
      float p0 = exp2f((s0[i] - m_[i]) * CS);
      float p1 = exp2f((s1[i] - m_[i]) * CS);
      l_[i] += p0 + p1;
      char* base = Ps[w] + row * 64;
      *(__bf16*)(base + ((unsigned)(c * 2) ^ swz)) = (__bf16)p0;
      *(__bf16*)(base + ((unsigned)(32 + c * 2) ^ swz)) = (__bf16)p1;
    }
    asm volatile("" ::: "memory");
    bf16x8 pa = *(const bf16x8*)(Ps[w] + c * 64 +
                 (((unsigned)(g * 16)) ^ ((unsigned)(c & 3) << 4)));
    // ---- O += P @ V ----
    const char* vread = KTs + g * 256 + c * 16;
#pragma unroll
    for (int f = 0; f < 16; f++) {
      bf16x8 vb = *(const bf16x8*)(vread + f * 1024);
      o[f] = MFMA(pa, vb, o[f]);
    }
  }
#undef STAGE

#pragma unroll
  for (int msk = 1; msk <= 8; msk <<= 1)
#pragma unroll
    for (int i = 0; i < 4; i++) l_[i] += __shfl_xor(l_[i], msk, 64);

  if (ksplit == NSPLIT - 1) {
    float* op = out + qrow0 * DD;
#pragma unroll
    for (int f = 0; f < 16; f++)
#pragma unroll
      for (int i = 0; i < 4; i++)
        op[(w * 16 + g * 4 + i) * DD + f * 16 + c] = o[f][i];
  } else {
    unsigned short* op = Op + (long)ksplit * (16384 * 256) + qrow0 * DD;
#pragma unroll
    for (int f = 0; f < 16; f++)
#pragma unroll
      for (int i = 0; i < 4; i++)
        op[(w * 16 + g * 4 + i) * DD + f * 16 + c] = f2bf(o[f][i]);
  }
  if (c == 0) {
    float* mlp = ML + (qg * NSPLIT + ksplit) * 128;
#pragma unroll
    for (int i = 0; i < 4; i++) {
      mlp[w * 16 + g * 4 + i] = m_[i];
      mlp[64 + w * 16 + g * 4 + i] = l_[i];
    }
  }
}

// ---------- merge the NSPLIT key-split partials + residual ----------
template <int NSPLIT>
__global__ __launch_bounds__(256) void merge_kernel(
    const unsigned short* __restrict__ Op, const float* __restrict__ ML,
    const unsigned short* __restrict__ Qb, float* __restrict__ out) {
  const float CS = 0.03125f * 1.4426950408889634f;
  const long gid = (long)blockIdx.x * 256 + threadIdx.x;
  const long idx = gid * 8;
  const int row = (int)(idx >> 8);
  const int qg = row >> 6, qr = row & 63;
  const float* mlb = ML + (long)(qg * NSPLIT) * 128;
  float mv[NSPLIT], lv[NSPLIT];
#pragma unroll
  for (int k = 0; k < NSPLIT; k++) {
    mv[k] = mlb[k * 128 + qr];
    lv[k] = mlb[k * 128 + 64 + qr];
  }
  float M = mv[0];
#pragma unroll
  for (int k = 1; k < NSPLIT; k++) M = fmaxf(M, mv[k]);
  float ek[NSPLIT], wsum = 0.f;
#pragma unroll
  for (int k = 0; k < NSPLIT; k++) {
    ek[k] = exp2f((mv[k] - M) * CS);
    wsum += ek[k] * lv[k];
  }
  const float inv = 1.0f / wsum;
  float acc[8];
  {
    f32x4 pa = *(const f32x4*)(out + idx);
    f32x4 pb = *(const f32x4*)(out + idx + 4);
#pragma unroll
    for (int e = 0; e < 4; e++) {
      acc[e] = ek[NSPLIT - 1] * pa[e];
      acc[4 + e] = ek[NSPLIT - 1] * pb[e];
    }
  }
#pragma unroll
  for (int k = 0; k < NSPLIT - 1; k++) {
    u16x8 p = *(const u16x8*)(Op + (long)k * (16384 * 256) + idx);
#pragma unroll
    for (int e = 0; e < 8; e++) acc[e] += ek[k] * bf2f(p[e]);
  }
  u16x8 qv = *(const u16x8*)(Qb + idx);
  f32x4 ra, rb;
#pragma unroll
  for (int e = 0; e < 4; e++) ra[e] = acc[e] * inv + bf2f(qv[e]);
#pragma unroll
  for (int e = 0; e < 4; e++) rb[e] = acc[4 + e] * inv + bf2f(qv[4 + e]);
  *(f32x4*)(out + idx) = ra;
  *(f32x4*)(out + idx + 4) = rb;
}

extern "C" void kernel_launch(void* const* d_in, const int* in_sizes, int n_in,
                              void* d_out, int out_size, void* d_ws, size_t ws_size,
                              hipStream_t stream) {
  (void)in_sizes; (void)n_in; (void)out_size;
  const float* data1 = (const float*)d_in[0];  // [8,2048,1024]
  const float* data2 = (const float*)d_in[1];  // [8,2048,256]
  const float* Wq = (const float*)d_in[2];     // [1024,256]
  const float* bq = (const float*)d_in[3];     // [256]
  const float* Wk = (const float*)d_in[4];     // [256,256]
  const float* bk = (const float*)d_in[5];     // [256]
  float* out = (float*)d_out;                  // [8,2048,256] f32

  char* ws = (char*)d_ws;
  unsigned short* Qb  = (unsigned short*)(ws);                        // 8 MB
  unsigned short* Kb  = (unsigned short*)(ws + (8ull << 20));         // 8 MB
  unsigned short* KTb = (unsigned short*)(ws + (16ull << 20));        // 8 MB
  unsigned short* WqT = (unsigned short*)(ws + (24ull << 20));        // 512 KB
  unsigned short* WkT = (unsigned short*)(ws + (24ull << 20) + (512u << 10));  // 128 KB
  unsigned short* Op  = (unsigned short*)(ws + (25ull << 20));        // up to 3 x 8 MB

  wt_kernel<<<dim3(1024), dim3(256), 0, stream>>>(Wq, WqT, 10, 256);
  wt_kernel<<<dim3(256), dim3(256), 0, stream>>>(Wk, WkT, 8, 256);
  proj_kernel<<<dim3(256), dim3(256), 0, stream>>>(data1, WqT, bq, Qb,
                                                   (unsigned short*)nullptr, 1024);
  proj_kernel<<<dim3(256), dim3(256), 0, stream>>>(data2, WkT, bk, Kb, KTb, 256);

  if (ws_size >= (50ull << 20)) {
    // 4-way key split: 1024 blocks, 36KB LDS -> 3 blocks/CU resident
    float* MLb = (float*)(ws + (49ull << 20));                        // 512 KB
    attn_kernel<4><<<dim3(1024), dim3(256), 0, stream>>>(Qb, Kb, KTb, Op, out, MLb);
    merge_kernel<4><<<dim3(2048), dim3(256), 0, stream>>>(Op, MLb, Qb, out);
  } else {
    // fallback: 2-way split, 512 blocks; fits in 33.25 MB
    float* MLb = (float*)(ws + (33ull << 20));                        // 256 KB
    attn_kernel<2><<<dim3(512), dim3(256), 0, stream>>>(Qb, Kb, KTb, Op, out, MLb);
    merge_kernel<2><<<dim3(2048), dim3(256), 0, stream>>>(Op, MLb, Qb, out);
  }
}

// Round 8
// 138.739 us; speedup vs baseline: 1.1747x; 1.1747x over previous
//
#include <hip/hip_runtime.h>
#include <hip/hip_bf16.h>

typedef __bf16 bf16x8 __attribute__((ext_vector_type(8)));
typedef unsigned short u16x8 __attribute__((ext_vector_type(8)));
typedef unsigned short u16x4 __attribute__((ext_vector_type(4)));
typedef float f32x4 __attribute__((ext_vector_type(4)));

#define MFMA(a, b, c) __builtin_amdgcn_mfma_f32_16x16x32_bf16(a, b, c, 0, 0, 0)

#define LQ 2048
#define DD 256

static __device__ __forceinline__ float bf2f(unsigned short u) {
  union { unsigned int i; float f; } x; x.i = ((unsigned int)u) << 16; return x.f;
}
static __device__ __forceinline__ unsigned short f2bf(float f) {
  union { float f; unsigned int i; } x; x.f = f;
  unsigned int r = x.i + 0x7fffu + ((x.i >> 16) & 1u);  // RNE
  return (unsigned short)(r >> 16);
}
static __device__ __forceinline__ void gll16(const void* g, void* l) {
  __builtin_amdgcn_global_load_lds(
      (const __attribute__((address_space(1))) unsigned int*)g,
      (__attribute__((address_space(3))) unsigned int*)l, 16, 0, 0);
}

// ---------- fused weight transposes: Wq,Wk f32 [K][256] -> bf16 [256][K] ----------
__global__ void wt2_kernel(const float* __restrict__ Wq, unsigned short* __restrict__ WqT,
                           const float* __restrict__ Wk, unsigned short* __restrict__ WkT) {
  int id = blockIdx.x * 256 + threadIdx.x;
  if (id < 262144) {                 // Wq: 1024x256
    int n = id >> 10, k = id & 1023;
    WqT[id] = f2bf(Wq[k * 256 + n]);
  } else {                           // Wk: 256x256
    int j = id - 262144;
    int n = j >> 8, k = j & 255;
    WkT[j] = f2bf(Wk[k * 256 + n]);
  }
}

// ---------- projection GEMM: 64x128 tile, 2 blocks/CU ----------
// out bf16[M][256] = A f32[M][Kd] @ W (+bias); W given as WT bf16 [256][Kd].
// Optionally also writes outT bf16 [b][256][2048] (K-proj).
__global__ __launch_bounds__(256) void proj_kernel(
    const float* __restrict__ A, const unsigned short* __restrict__ WT,
    const float* __restrict__ bias, unsigned short* __restrict__ outb,
    unsigned short* __restrict__ outT, int Kd) {
  __shared__ unsigned short A_s[64 * 32];
  __shared__ unsigned short B_s[128 * 32];
  const int tid = threadIdx.x;
  const int w = tid >> 6, lane = tid & 63, g = lane >> 4, c = lane & 15;
  const int m0 = (blockIdx.x >> 1) * 64, n0 = (blockIdx.x & 1) * 128;
  const int wr = (w >> 1) * 32, wc = (w & 1) * 64;

  f32x4 acc[2][4];
  const f32x4 z4 = {0.f, 0.f, 0.f, 0.f};
  for (int i = 0; i < 2; i++)
    for (int j = 0; j < 4; j++) acc[i][j] = z4;

  const int row_a = tid >> 2, k0a = (tid & 3) * 8;       // A: 64 rows, 8 elem/thread
  const int row_b = tid >> 1, k0b = (tid & 1) * 16;      // B: 128 rows, 16 elem/thread
  const unsigned swz_a = (unsigned)((row_a & 7) << 4);
  const unsigned swz_b = (unsigned)((row_b & 7) << 4);
  const int nk = Kd >> 5;
  for (int ks = 0; ks < nk; ks++) {
    {
      const float* src = A + (long)(m0 + row_a) * Kd + ks * 32 + k0a;
      f32x4 a0 = *(const f32x4*)(src);
      f32x4 a1 = *(const f32x4*)(src + 4);
      bf16x8 t0;
#pragma unroll
      for (int j = 0; j < 4; j++) { t0[j] = (__bf16)a0[j]; t0[4 + j] = (__bf16)a1[j]; }
      *(bf16x8*)((char*)A_s + (((unsigned)(row_a * 64 + k0a * 2)) ^ swz_a)) = t0;
      const unsigned short* srcB = WT + (long)(n0 + row_b) * Kd + ks * 32 + k0b;
      u16x8 b0 = *(const u16x8*)srcB;
      u16x8 b1 = *(const u16x8*)(srcB + 8);
      *(u16x8*)((char*)B_s + (((unsigned)(row_b * 64 + k0b * 2)) ^ swz_b)) = b0;
      *(u16x8*)((char*)B_s + (((unsigned)(row_b * 64 + k0b * 2 + 16)) ^ swz_b)) = b1;
    }
    __syncthreads();
    bf16x8 af[2], bfr[4];
    for (int rf = 0; rf < 2; rf++) {
      int row = wr + rf * 16 + c;
      af[rf] = *(const bf16x8*)((char*)A_s +
                (((unsigned)(row * 64 + g * 16)) ^ ((row & 7) << 4)));
    }
    for (int cf = 0; cf < 4; cf++) {
      int row = wc + cf * 16 + c;
      bfr[cf] = *(const bf16x8*)((char*)B_s +
                (((unsigned)(row * 64 + g * 16)) ^ ((row & 7) << 4)));
    }
    for (int rf = 0; rf < 2; rf++)
      for (int cf = 0; cf < 4; cf++)
        acc[rf][cf] = MFMA(af[rf], bfr[cf], acc[rf][cf]);
    __syncthreads();
  }
  for (int cf = 0; cf < 4; cf++) {
    const int col = n0 + wc + cf * 16 + c;
    const float bv = bias[col];
    for (int rf = 0; rf < 2; rf++) {
      const int row0 = m0 + wr + rf * 16 + g * 4;
      unsigned short pk[4];
      for (int i = 0; i < 4; i++) {
        float v = acc[rf][cf][i] + bv;
        pk[i] = f2bf(v);
        outb[(long)(row0 + i) * 256 + col] = pk[i];
      }
      if (outT) {
        const int b = row0 >> 11;
        const int key0 = row0 & 2047;
        unsigned long long packed = (unsigned long long)pk[0] |
                                    ((unsigned long long)pk[1] << 16) |
                                    ((unsigned long long)pk[2] << 32) |
                                    ((unsigned long long)pk[3] << 48);
        *(unsigned long long*)(outT + ((long)(b * 256 + col) * LQ + key0)) = packed;
      }
    }
  }
}

// ---------- flash attention (R5 structure): 16 rows/wave, dbuf LDS, 2-way split --
// Ks slot (ks,g,key): byte ks*2048+g*512+key*16 = K[k0+key][ks*32+g*8..+8]
// KTs slot (f,g,c):   byte f*1024+g*256+c*16   = KT[f*16+c][k0+g*8..+8]
__global__ __launch_bounds__(256, 2) void attn_kernel(
    const unsigned short* __restrict__ Qb, const unsigned short* __restrict__ Kb,
    const unsigned short* __restrict__ KTb, unsigned short* __restrict__ Op0,
    float* __restrict__ out, float* __restrict__ ML) {
  __shared__ char Ks[2][16384];
  __shared__ char KTs[2][16384];
  __shared__ char Ps[4][1024];
  const int tid = threadIdx.x;
  const int w = tid >> 6, lane = tid & 63, g = lane >> 4, c = lane & 15;
  const int lid = ((blockIdx.x & 7) << 6) + (blockIdx.x >> 3);  // XCD-chunked
  const int ksplit = lid & 1, qg = lid >> 1;   // qg 0..255
  const int b = qg >> 5;
  const long qrow0 = (long)qg * 64;
  const int kbase = ksplit * 1024;
  const float CS = 0.03125f * 1.4426950408889634f;  // SCALE * log2(e)
  const float THRM = 8.0f / CS;                     // defer-max threshold (raw)

  bf16x8 qa[8];
  {
    const unsigned short* qr = Qb + (qrow0 + w * 16 + c) * DD + g * 8;
#pragma unroll
    for (int ks = 0; ks < 8; ks++) qa[ks] = *(const bf16x8*)(qr + ks * 32);
  }
  f32x4 o[16];
  const f32x4 z4 = {0.f, 0.f, 0.f, 0.f};
#pragma unroll
  for (int f = 0; f < 16; f++) o[f] = z4;
  float m_[4] = {-1e30f, -1e30f, -1e30f, -1e30f};
  float l_[4] = {0.f, 0.f, 0.f, 0.f};

  const char* kb_b = (const char*)(Kb + (long)b * LQ * DD);
  const char* kt_b = (const char*)(KTb + (long)b * DD * LQ);

  const int ks_w = w >> 1;
  const int kg_w = ((w & 1) << 1) + (lane >> 5);
  const int kkey = lane & 31;

#define STAGE(buf, kt_)                                                         \
  {                                                                             \
    const int k0_ = kbase + (kt_) * 32;                                         \
    _Pragma("unroll") for (int i = 0; i < 4; i++) {                             \
      gll16(kb_b + (long)(k0_ + kkey) * 512 + (i * 2 + ks_w) * 64 + kg_w * 16,  \
            Ks[buf] + i * 4096 + w * 1024);                                     \
    }                                                                           \
    _Pragma("unroll") for (int i = 0; i < 4; i++) {                             \
      const int f_ = i * 4 + w;                                                 \
      gll16(kt_b + (long)(f_ * 16 + c) * 4096 + (long)k0_ * 2 + g * 16,         \
            KTs[buf] + f_ * 1024);                                              \
    }                                                                           \
  }

  STAGE(0, 0);
  for (int kt = 0; kt < 32; kt++) {
    const int cur = kt & 1;
    __syncthreads();
    if (kt + 1 < 32) STAGE(cur ^ 1, kt + 1);

    // ---- S = Q K^T ----
    const char* kread = Ks[cur] + g * 512 + c * 16;
    f32x4 s0 = z4, s1 = z4;
    __builtin_amdgcn_s_setprio(1);
#pragma unroll
    for (int ks = 0; ks < 8; ks++) {
      bf16x8 kb0 = *(const bf16x8*)(kread + ks * 2048);
      bf16x8 kb1 = *(const bf16x8*)(kread + ks * 2048 + 256);
      s0 = MFMA(qa[ks], kb0, s0);
      s1 = MFMA(qa[ks], kb1, s1);
    }
    __builtin_amdgcn_s_setprio(0);
    // ---- online softmax with defer-max ----
    float m2[4];
#pragma unroll
    for (int i = 0; i < 4; i++) m2[i] = fmaxf(s0[i], s1[i]);
#pragma unroll
    for (int msk = 1; msk <= 8; msk <<= 1)
#pragma unroll
      for (int i = 0; i < 4; i++) m2[i] = fmaxf(m2[i], __shfl_xor(m2[i], msk, 64));
    bool grew = (m2[0] > m_[0] + THRM) | (m2[1] > m_[1] + THRM) |
                (m2[2] > m_[2] + THRM) | (m2[3] > m_[3] + THRM);
    if (__any(grew)) {
#pragma unroll
      for (int i = 0; i < 4; i++) {
        float mn = fmaxf(m_[i], m2[i]);
        float al = exp2f((m_[i] - mn) * CS);
        m_[i] = mn;
        l_[i] *= al;
#pragma unroll
        for (int f = 0; f < 16; f++) o[f][i] *= al;
      }
    }
    // ---- P -> LDS, read back as A-frag ----
#pragma unroll
    for (int i = 0; i < 4; i++) {
      const int row = 4 * g + i;
      const unsigned swz = (unsigned)(i << 4);
      float p0 = exp2f((s0[i] - m_[i]) * CS);
      float p1 = exp2f((s1[i] - m_[i]) * CS);
      l_[i] += p0 + p1;
      char* base = Ps[w] + row * 64;
      *(__bf16*)(base + ((unsigned)(c * 2) ^ swz)) = (__bf16)p0;
      *(__bf16*)(base + ((unsigned)(32 + c * 2) ^ swz)) = (__bf16)p1;
    }
    asm volatile("" ::: "memory");
    bf16x8 pa = *(const bf16x8*)(Ps[w] + c * 64 +
                 (((unsigned)(g * 16)) ^ ((unsigned)(c & 3) << 4)));
    // ---- O += P @ V ----
    const char* vread = KTs[cur] + g * 256 + c * 16;
    __builtin_amdgcn_s_setprio(1);
#pragma unroll
    for (int f = 0; f < 16; f++) {
      bf16x8 vb = *(const bf16x8*)(vread + f * 1024);
      o[f] = MFMA(pa, vb, o[f]);
    }
    __builtin_amdgcn_s_setprio(0);
  }
#undef STAGE

#pragma unroll
  for (int msk = 1; msk <= 8; msk <<= 1)
#pragma unroll
    for (int i = 0; i < 4; i++) l_[i] += __shfl_xor(l_[i], msk, 64);

  if (ksplit) {
    float* op = out + qrow0 * DD;
#pragma unroll
    for (int f = 0; f < 16; f++)
#pragma unroll
      for (int i = 0; i < 4; i++)
        op[(w * 16 + g * 4 + i) * DD + f * 16 + c] = o[f][i];
  } else {
    unsigned short* op = Op0 + qrow0 * DD;
#pragma unroll
    for (int f = 0; f < 16; f++)
#pragma unroll
      for (int i = 0; i < 4; i++)
        op[(w * 16 + g * 4 + i) * DD + f * 16 + c] = f2bf(o[f][i]);
  }
  if (c == 0) {
    float* mlp = ML + (qg * 2 + ksplit) * 128;
#pragma unroll
    for (int i = 0; i < 4; i++) {
      mlp[w * 16 + g * 4 + i] = m_[i];
      mlp[64 + w * 16 + g * 4 + i] = l_[i];
    }
  }
}

// ---------- merge the two key-split partials + residual ----------
__global__ __launch_bounds__(256) void merge_kernel(
    const unsigned short* __restrict__ Op0, const float* __restrict__ ML,
    const unsigned short* __restrict__ Qb, float* __restrict__ out) {
  const float CS = 0.03125f * 1.4426950408889634f;
  const long gid = (long)blockIdx.x * 256 + threadIdx.x;
  const long idx = gid * 8;
  const int row = (int)(idx >> 8);
  const int qg = row >> 6, qr = row & 63;
  const float m0 = ML[(qg * 2) * 128 + qr], l0 = ML[(qg * 2) * 128 + 64 + qr];
  const float m1 = ML[(qg * 2 + 1) * 128 + qr], l1 = ML[(qg * 2 + 1) * 128 + 64 + qr];
  const float M = fmaxf(m0, m1);
  const float e0 = exp2f((m0 - M) * CS), e1 = exp2f((m1 - M) * CS);
  const float inv = 1.0f / (e0 * l0 + e1 * l1);
  u16x8 p0 = *(const u16x8*)(Op0 + idx);
  f32x4 p1a = *(const f32x4*)(out + idx);
  f32x4 p1b = *(const f32x4*)(out + idx + 4);
  u16x8 qv = *(const u16x8*)(Qb + idx);
  f32x4 ra, rb;
#pragma unroll
  for (int e = 0; e < 4; e++)
    ra[e] = (e0 * bf2f(p0[e]) + e1 * p1a[e]) * inv + bf2f(qv[e]);
#pragma unroll
  for (int e = 0; e < 4; e++)
    rb[e] = (e0 * bf2f(p0[4 + e]) + e1 * p1b[e]) * inv + bf2f(qv[4 + e]);
  *(f32x4*)(out + idx) = ra;
  *(f32x4*)(out + idx + 4) = rb;
}

extern "C" void kernel_launch(void* const* d_in, const int* in_sizes, int n_in,
                              void* d_out, int out_size, void* d_ws, size_t ws_size,
                              hipStream_t stream) {
  (void)in_sizes; (void)n_in; (void)out_size; (void)ws_size;
  const float* data1 = (const float*)d_in[0];  // [8,2048,1024]
  const float* data2 = (const float*)d_in[1];  // [8,2048,256]
  const float* Wq = (const float*)d_in[2];     // [1024,256]
  const float* bq = (const float*)d_in[3];     // [256]
  const float* Wk = (const float*)d_in[4];     // [256,256]
  const float* bk = (const float*)d_in[5];     // [256]
  float* out = (float*)d_out;                  // [8,2048,256] f32

  char* ws = (char*)d_ws;
  unsigned short* Qb  = (unsigned short*)(ws);                        // 8 MB
  unsigned short* Kb  = (unsigned short*)(ws + (8ull << 20));         // 8 MB
  unsigned short* KTb = (unsigned short*)(ws + (16ull << 20));        // 8 MB
  unsigned short* WqT = (unsigned short*)(ws + (24ull << 20));        // 512 KB
  unsigned short* WkT = (unsigned short*)(ws + (24ull << 20) + (512u << 10));  // 128 KB
  unsigned short* Op0 = (unsigned short*)(ws + (25ull << 20));        // 8 MB
  float*          MLb = (float*)(ws + (33ull << 20));                 // 256 KB

  wt2_kernel<<<dim3(1280), dim3(256), 0, stream>>>(Wq, WqT, Wk, WkT);
  proj_kernel<<<dim3(512), dim3(256), 0, stream>>>(data1, WqT, bq, Qb,
                                                   (unsigned short*)nullptr, 1024);
  proj_kernel<<<dim3(512), dim3(256), 0, stream>>>(data2, WkT, bk, Kb, KTb, 256);
  attn_kernel<<<dim3(512), dim3(256), 0, stream>>>(Qb, Kb, KTb, Op0, out, MLb);
  merge_kernel<<<dim3(2048), dim3(256), 0, stream>>>(Op0, MLb, Qb, out);
}

// Round 9
// 113.060 us; speedup vs baseline: 1.4415x; 1.2271x over previous
//
#include <hip/hip_runtime.h>
#include <hip/hip_bf16.h>

typedef __bf16 bf16x8 __attribute__((ext_vector_type(8)));
typedef __bf16 bf16x2 __attribute__((ext_vector_type(2)));
typedef unsigned short u16x8 __attribute__((ext_vector_type(8)));
typedef float f32x4 __attribute__((ext_vector_type(4)));
typedef float f32x16 __attribute__((ext_vector_type(16)));

#define MFMA(a, b, c) __builtin_amdgcn_mfma_f32_16x16x32_bf16(a, b, c, 0, 0, 0)
#define MFMA32(a, b, c) __builtin_amdgcn_mfma_f32_32x32x16_bf16(a, b, c, 0, 0, 0)

#define LQ 2048
#define DD 256

static __device__ __forceinline__ float bf2f(unsigned short u) {
  union { unsigned int i; float f; } x; x.i = ((unsigned int)u) << 16; return x.f;
}
static __device__ __forceinline__ unsigned short f2bf(float f) {
  union { float f; unsigned int i; } x; x.f = f;
  unsigned int r = x.i + 0x7fffu + ((x.i >> 16) & 1u);  // RNE
  return (unsigned short)(r >> 16);
}
static __device__ __forceinline__ void gll16(const void* g, void* l) {
  __builtin_amdgcn_global_load_lds(
      (const __attribute__((address_space(1))) unsigned int*)g,
      (__attribute__((address_space(3))) unsigned int*)l, 16, 0, 0);
}
static __device__ __forceinline__ unsigned pack2(float a, float b) {
  union { bf16x2 v; unsigned u; } x;
  x.v[0] = (__bf16)a; x.v[1] = (__bf16)b;   // compiler -> v_cvt_pk_bf16_f32
  return x.u;
}

// ---------- fused weight transposes: Wq,Wk f32 [K][256] -> bf16 [256][K] ----------
__global__ void wt2_kernel(const float* __restrict__ Wq, unsigned short* __restrict__ WqT,
                           const float* __restrict__ Wk, unsigned short* __restrict__ WkT) {
  int id = blockIdx.x * 256 + threadIdx.x;
  if (id < 262144) {                 // Wq: 1024x256
    int n = id >> 10, k = id & 1023;
    WqT[id] = f2bf(Wq[k * 256 + n]);
  } else {                           // Wk: 256x256
    int j = id - 262144;
    int n = j >> 8, k = j & 255;
    WkT[j] = f2bf(Wk[k * 256 + n]);
  }
}

// ---------- projection GEMM: 64x128 tile (R8 structure) ----------
__global__ __launch_bounds__(256) void proj_kernel(
    const float* __restrict__ A, const unsigned short* __restrict__ WT,
    const float* __restrict__ bias, unsigned short* __restrict__ outb,
    unsigned short* __restrict__ outT, int Kd) {
  __shared__ unsigned short A_s[64 * 32];
  __shared__ unsigned short B_s[128 * 32];
  const int tid = threadIdx.x;
  const int w = tid >> 6, lane = tid & 63, g = lane >> 4, c = lane & 15;
  const int m0 = (blockIdx.x >> 1) * 64, n0 = (blockIdx.x & 1) * 128;
  const int wr = (w >> 1) * 32, wc = (w & 1) * 64;

  f32x4 acc[2][4];
  const f32x4 z4 = {0.f, 0.f, 0.f, 0.f};
  for (int i = 0; i < 2; i++)
    for (int j = 0; j < 4; j++) acc[i][j] = z4;

  const int row_a = tid >> 2, k0a = (tid & 3) * 8;
  const int row_b = tid >> 1, k0b = (tid & 1) * 16;
  const unsigned swz_a = (unsigned)((row_a & 7) << 4);
  const unsigned swz_b = (unsigned)((row_b & 7) << 4);
  const int nk = Kd >> 5;
  for (int ks = 0; ks < nk; ks++) {
    {
      const float* src = A + (long)(m0 + row_a) * Kd + ks * 32 + k0a;
      f32x4 a0 = *(const f32x4*)(src);
      f32x4 a1 = *(const f32x4*)(src + 4);
      bf16x8 t0;
#pragma unroll
      for (int j = 0; j < 4; j++) { t0[j] = (__bf16)a0[j]; t0[4 + j] = (__bf16)a1[j]; }
      *(bf16x8*)((char*)A_s + (((unsigned)(row_a * 64 + k0a * 2)) ^ swz_a)) = t0;
      const unsigned short* srcB = WT + (long)(n0 + row_b) * Kd + ks * 32 + k0b;
      u16x8 b0 = *(const u16x8*)srcB;
      u16x8 b1 = *(const u16x8*)(srcB + 8);
      *(u16x8*)((char*)B_s + (((unsigned)(row_b * 64 + k0b * 2)) ^ swz_b)) = b0;
      *(u16x8*)((char*)B_s + (((unsigned)(row_b * 64 + k0b * 2 + 16)) ^ swz_b)) = b1;
    }
    __syncthreads();
    bf16x8 af[2], bfr[4];
    for (int rf = 0; rf < 2; rf++) {
      int row = wr + rf * 16 + c;
      af[rf] = *(const bf16x8*)((char*)A_s +
                (((unsigned)(row * 64 + g * 16)) ^ ((row & 7) << 4)));
    }
    for (int cf = 0; cf < 4; cf++) {
      int row = wc + cf * 16 + c;
      bfr[cf] = *(const bf16x8*)((char*)B_s +
                (((unsigned)(row * 64 + g * 16)) ^ ((row & 7) << 4)));
    }
    for (int rf = 0; rf < 2; rf++)
      for (int cf = 0; cf < 4; cf++)
        acc[rf][cf] = MFMA(af[rf], bfr[cf], acc[rf][cf]);
    __syncthreads();
  }
  for (int cf = 0; cf < 4; cf++) {
    const int col = n0 + wc + cf * 16 + c;
    const float bv = bias[col];
    for (int rf = 0; rf < 2; rf++) {
      const int row0 = m0 + wr + rf * 16 + g * 4;
      unsigned short pk[4];
      for (int i = 0; i < 4; i++) {
        float v = acc[rf][cf][i] + bv;
        pk[i] = f2bf(v);
        outb[(long)(row0 + i) * 256 + col] = pk[i];
      }
      if (outT) {
        const int b = row0 >> 11;
        const int key0 = row0 & 2047;
        unsigned long long packed = (unsigned long long)pk[0] |
                                    ((unsigned long long)pk[1] << 16) |
                                    ((unsigned long long)pk[2] << 32) |
                                    ((unsigned long long)pk[3] << 48);
        *(unsigned long long*)(outT + ((long)(b * 256 + col) * LQ + key0)) = packed;
      }
    }
  }
}

// ---------- flash attention: swapped-operand 32x32 MFMA, in-register softmax --
// Wave owns 32 q-rows (q = lane&31). Block = 4 waves = 128 rows, NSPLIT key-split.
// QK: S[key][q] = mfma32(K_frag, Q_frag): lane holds 16 keys for its q.
// PV: O[d][q]  = mfma32(KT_frag, P_frag): rescale/l are per-lane scalars.
// Ks slot (s):    byte s*1024 + lane*16      = K[k0+(l&31)][s*16+(l>>5)*8 ..+8]
// KTs slot (t,h): byte (t*2+h)*1024 + lane*16 = KT[t*32+(l&31)][k0+h*16+(l>>5)*8 ..+8]
template <int NSPLIT>
__global__ __launch_bounds__(256, 2) void attn_kernel(
    const unsigned short* __restrict__ Qb, const unsigned short* __restrict__ Kb,
    const unsigned short* __restrict__ KTb, unsigned short* __restrict__ Op,
    float* __restrict__ out, float* __restrict__ ML) {
  constexpr int KS = 2048 / NSPLIT;
  constexpr int NT = KS / 32;
  constexpr int NBLK = 128 * NSPLIT;
  __shared__ char Ks[2][16384];
  __shared__ char KTs[2][16384];
  const int tid = threadIdx.x;
  const int w = tid >> 6, lane = tid & 63;
  const int l5 = lane >> 5, q31 = lane & 31;
  const int lid = (blockIdx.x & 7) * (NBLK / 8) + (blockIdx.x >> 3);  // XCD-chunked
  const int ksplit = lid & (NSPLIT - 1), qg = lid / NSPLIT;  // qg 0..127; batch==XCD
  const int b = qg >> 4;
  const long qrow0 = (long)qg * 128;
  const int kbase = ksplit * KS;
  const float CS = 0.03125f * 1.4426950408889634f;  // SCALE * log2(e)
  const float THRM = 8.0f / CS;                     // defer-max threshold (raw)

  // Q B-fragments: 16 d-slices, persistent (64 VGPR)
  bf16x8 qf[16];
  {
    const unsigned short* qp = Qb + (qrow0 + w * 32 + q31) * DD + l5 * 8;
#pragma unroll
    for (int s = 0; s < 16; s++) qf[s] = *(const bf16x8*)(qp + s * 16);
  }
  f32x16 o[8];
#pragma unroll
  for (int t = 0; t < 8; t++) o[t] = (f32x16)(0.f);
  float m_ = -1e30f, l_ = 0.f;

  const char* kb_b = (const char*)(Kb + (long)b * LQ * DD);
  const char* kt_b = (const char*)(KTb + (long)b * DD * LQ);

#define STAGE(buf, kt_)                                                          \
  {                                                                              \
    const int k0_ = kbase + (kt_) * 32;                                          \
    const char* kbp_ = kb_b + (long)(k0_ + q31) * 512 + l5 * 16;                 \
    _Pragma("unroll") for (int i = 0; i < 4; i++) {                              \
      const int sl = w * 4 + i;                                                  \
      gll16(kbp_ + sl * 32, Ks[buf] + sl * 1024);                                \
    }                                                                            \
    _Pragma("unroll") for (int i = 0; i < 4; i++) {                              \
      const int th = w * 4 + i;                                                  \
      gll16(kt_b + (long)((th >> 1) * 32 + q31) * 4096 + (long)k0_ * 2 +         \
                (th & 1) * 32 + l5 * 16,                                         \
            KTs[buf] + th * 1024);                                               \
    }                                                                            \
  }

  STAGE(0, 0);
  for (int kt = 0; kt < NT; kt++) {
    const int cur = kt & 1;
    __syncthreads();                       // staged tile visible; prev reads done
    if (kt + 1 < NT) STAGE(cur ^ 1, kt + 1);

    // ---- S[key][q] = K x Q^T ----
    const char* kr = Ks[cur] + lane * 16;
    f32x16 s = (f32x16)(0.f);
#pragma unroll
    for (int sl = 0; sl < 16; sl++) {
      bf16x8 kf = *(const bf16x8*)(kr + sl * 1024);
      s = MFMA32(kf, qf[sl], s);
    }

    // ---- in-register online softmax (lane owns 16 of 32 keys for q=lane&31) ----
    float mx = s[0];
#pragma unroll
    for (int r = 1; r < 16; r++) mx = fmaxf(mx, s[r]);
    mx = fmaxf(mx, __shfl_xor(mx, 32));
    if (__any(mx > m_ + THRM)) {
      float mn = fmaxf(m_, mx);
      float al = exp2f((m_ - mn) * CS);
      m_ = mn;
      l_ *= al;
#pragma unroll
      for (int t = 0; t < 8; t++) o[t] *= al;
    }
    const float mCS = m_ * CS;
    float p[16];
    float ls = 0.f;
#pragma unroll
    for (int r = 0; r < 16; r++) {
      p[r] = exp2f(s[r] * CS - mCS);
      ls += p[r];
    }
    l_ += ls;

    // ---- P -> bf16 packs -> B-fragments (keys made k-slot-contiguous) ----
    unsigned pk[8];
#pragma unroll
    for (int j = 0; j < 8; j++) pk[j] = pack2(p[2 * j], p[2 * j + 1]);
    unsigned x0 = (unsigned)__shfl_xor((int)pk[0], 32);
    unsigned x1 = (unsigned)__shfl_xor((int)pk[1], 32);
    unsigned x2 = (unsigned)__shfl_xor((int)pk[2], 32);
    unsigned x3 = (unsigned)__shfl_xor((int)pk[3], 32);
    unsigned x4 = (unsigned)__shfl_xor((int)pk[4], 32);
    unsigned x5 = (unsigned)__shfl_xor((int)pk[5], 32);
    unsigned x6 = (unsigned)__shfl_xor((int)pk[6], 32);
    unsigned x7 = (unsigned)__shfl_xor((int)pk[7], 32);
    union { unsigned u[4]; bf16x8 v; } pf0, pf1;
    const bool hi = (l5 != 0);
    pf0.u[0] = hi ? x2 : pk[0];
    pf0.u[1] = hi ? x3 : pk[1];
    pf0.u[2] = hi ? pk[2] : x0;
    pf0.u[3] = hi ? pk[3] : x1;
    pf1.u[0] = hi ? x6 : pk[4];
    pf1.u[1] = hi ? x7 : pk[5];
    pf1.u[2] = hi ? pk[6] : x4;
    pf1.u[3] = hi ? pk[7] : x5;

    // ---- O[d][q] += V^T x P ----
    const char* vr = KTs[cur] + lane * 16;
#pragma unroll
    for (int t = 0; t < 8; t++) {
      bf16x8 v0 = *(const bf16x8*)(vr + (t * 2) * 1024);
      bf16x8 v1 = *(const bf16x8*)(vr + (t * 2 + 1) * 1024);
      o[t] = MFMA32(v0, pf0.v, o[t]);
      o[t] = MFMA32(v1, pf1.v, o[t]);
    }
  }
#undef STAGE

  l_ += __shfl_xor(l_, 32);   // combine the two key-halves

  // ---- write partial: O[d][q] -> row-major [q][d] via per-reg scatter ----
  const long orow = (qrow0 + w * 32 + q31) * (long)DD;
  if (ksplit == NSPLIT - 1) {
    float* op = out + orow;
#pragma unroll
    for (int t = 0; t < 8; t++)
#pragma unroll
      for (int r = 0; r < 16; r++)
        op[t * 32 + (r & 3) + 8 * (r >> 2) + 4 * l5] = o[t][r];
  } else {
    unsigned short* opb = Op + (long)ksplit * (16384 * 256) + orow;
#pragma unroll
    for (int t = 0; t < 8; t++)
#pragma unroll
      for (int r = 0; r < 16; r++)
        opb[t * 32 + (r & 3) + 8 * (r >> 2) + 4 * l5] = f2bf(o[t][r]);
  }
  if (lane < 32) {
    float* mlp = ML + (long)(qg * NSPLIT + ksplit) * 256;
    mlp[w * 32 + q31] = m_;
    mlp[128 + w * 32 + q31] = l_;
  }
}

// ---------- merge the NSPLIT key-split partials + residual (128-row groups) ----
template <int NSPLIT>
__global__ __launch_bounds__(256) void merge_kernel(
    const unsigned short* __restrict__ Op, const float* __restrict__ ML,
    const unsigned short* __restrict__ Qb, float* __restrict__ out) {
  const float CS = 0.03125f * 1.4426950408889634f;
  const long gid = (long)blockIdx.x * 256 + threadIdx.x;
  const long idx = gid * 8;
  const int row = (int)(idx >> 8);
  const int qg = row >> 7, qr = row & 127;
  const float* mlb = ML + (long)(qg * NSPLIT) * 256;
  float mv[NSPLIT], lv[NSPLIT];
#pragma unroll
  for (int k = 0; k < NSPLIT; k++) {
    mv[k] = mlb[k * 256 + qr];
    lv[k] = mlb[k * 256 + 128 + qr];
  }
  float M = mv[0];
#pragma unroll
  for (int k = 1; k < NSPLIT; k++) M = fmaxf(M, mv[k]);
  float ek[NSPLIT], wsum = 0.f;
#pragma unroll
  for (int k = 0; k < NSPLIT; k++) {
    ek[k] = exp2f((mv[k] - M) * CS);
    wsum += ek[k] * lv[k];
  }
  const float inv = 1.0f / wsum;
  float acc[8];
  {
    f32x4 pa = *(const f32x4*)(out + idx);
    f32x4 pb = *(const f32x4*)(out + idx + 4);
#pragma unroll
    for (int e = 0; e < 4; e++) {
      acc[e] = ek[NSPLIT - 1] * pa[e];
      acc[4 + e] = ek[NSPLIT - 1] * pb[e];
    }
  }
#pragma unroll
  for (int k = 0; k < NSPLIT - 1; k++) {
    u16x8 p = *(const u16x8*)(Op + (long)k * (16384 * 256) + idx);
#pragma unroll
    for (int e = 0; e < 8; e++) acc[e] += ek[k] * bf2f(p[e]);
  }
  u16x8 qv = *(const u16x8*)(Qb + idx);
  f32x4 ra, rb;
#pragma unroll
  for (int e = 0; e < 4; e++) ra[e] = acc[e] * inv + bf2f(qv[e]);
#pragma unroll
  for (int e = 0; e < 4; e++) rb[e] = acc[4 + e] * inv + bf2f(qv[4 + e]);
  *(f32x4*)(out + idx) = ra;
  *(f32x4*)(out + idx + 4) = rb;
}

extern "C" void kernel_launch(void* const* d_in, const int* in_sizes, int n_in,
                              void* d_out, int out_size, void* d_ws, size_t ws_size,
                              hipStream_t stream) {
  (void)in_sizes; (void)n_in; (void)out_size;
  const float* data1 = (const float*)d_in[0];  // [8,2048,1024]
  const float* data2 = (const float*)d_in[1];  // [8,2048,256]
  const float* Wq = (const float*)d_in[2];     // [1024,256]
  const float* bq = (const float*)d_in[3];     // [256]
  const float* Wk = (const float*)d_in[4];     // [256,256]
  const float* bk = (const float*)d_in[5];     // [256]
  float* out = (float*)d_out;                  // [8,2048,256] f32

  char* ws = (char*)d_ws;
  unsigned short* Qb  = (unsigned short*)(ws);                        // 8 MB
  unsigned short* Kb  = (unsigned short*)(ws + (8ull << 20));         // 8 MB
  unsigned short* KTb = (unsigned short*)(ws + (16ull << 20));        // 8 MB
  unsigned short* WqT = (unsigned short*)(ws + (24ull << 20));        // 512 KB
  unsigned short* WkT = (unsigned short*)(ws + (24ull << 20) + (512u << 10));  // 128 KB
  unsigned short* Op  = (unsigned short*)(ws + (25ull << 20));        // up to 3 x 8 MB

  wt2_kernel<<<dim3(1280), dim3(256), 0, stream>>>(Wq, WqT, Wk, WkT);
  proj_kernel<<<dim3(512), dim3(256), 0, stream>>>(data1, WqT, bq, Qb,
                                                   (unsigned short*)nullptr, 1024);
  proj_kernel<<<dim3(512), dim3(256), 0, stream>>>(data2, WkT, bk, Kb, KTb, 256);

  if (ws_size >= (50ull << 20)) {
    float* MLb = (float*)(ws + (49ull << 20));                        // 512 KB
    attn_kernel<4><<<dim3(512), dim3(256), 0, stream>>>(Qb, Kb, KTb, Op, out, MLb);
    merge_kernel<4><<<dim3(2048), dim3(256), 0, stream>>>(Op, MLb, Qb, out);
  } else {
    float* MLb = (float*)(ws + (33ull << 20));                        // 256 KB
    attn_kernel<2><<<dim3(256), dim3(256), 0, stream>>>(Qb, Kb, KTb, Op, out, MLb);
    merge_kernel<2><<<dim3(2048), dim3(256), 0, stream>>>(Op, MLb, Qb, out);
  }
}